// Round 2
// baseline (541.333 us; speedup 1.0000x reference)
//
#include <hip/hip_runtime.h>

#define N_NODES 50000
#define N_EDGES 800000
#define IN_DIM  1200
#define OUT_DIM 300
#define XS      300      // x row stride in f32 (1200 B rows, 16B-aligned)

typedef __attribute__((ext_vector_type(8))) short short8;
typedef __attribute__((ext_vector_type(4))) float f32x4;

__device__ __forceinline__ short f2bf(float f) {
  unsigned u = __builtin_bit_cast(unsigned, f);
  u += 0x7fffu + ((u >> 16) & 1u);            // RNE
  return (short)(u >> 16);
}
__device__ __forceinline__ float lrelu(float v) { return v > 0.f ? v : 0.2f * v; }

__device__ __forceinline__ float wredMaxF(float v) {
  #pragma unroll
  for (int o = 32; o > 0; o >>= 1) v = fmaxf(v, __shfl_xor(v, o));
  return v;
}
__device__ __forceinline__ float wredSumF(float v) {
  #pragma unroll
  for (int o = 32; o > 0; o >>= 1) v += __shfl_xor(v, o);
  return v;
}

// ---------------- GEMM: x[50000,300] = z[50000,1200] @ W[300,1200]^T (bf16 MFMA)
__global__ __launch_bounds__(256) void gemm_x(const float* __restrict__ z,
                                              const float* __restrict__ W,
                                              float* __restrict__ x) {
  __shared__ unsigned short As[64 * 40];    // 64 rows x 32k, stride 40 (pad vs bank conflict)
  __shared__ unsigned short Bs[304 * 40];   // 304 n-rows x 32k, stride 40

  const int tid  = threadIdx.x;
  const int lane = tid & 63;
  const int wid  = tid >> 6;
  const int m0   = blockIdx.x * 64;
  const int lr   = lane & 15;
  const int lk   = (lane >> 4) * 8;

  f32x4 zero4 = {0.f, 0.f, 0.f, 0.f};
  f32x4 acc[19];
  #pragma unroll
  for (int t = 0; t < 19; ++t) acc[t] = zero4;

  const int ar = tid >> 2;          // 0..63
  const int ac = (tid & 3) * 8;     // 0,8,16,24

  for (int kt = 0; kt < 38; ++kt) {
    const int k0 = kt * 32;
    // stage A (z tile), f32 -> bf16
    {
      short8 v = {0,0,0,0,0,0,0,0};
      int m = m0 + ar, k = k0 + ac;
      if (m < N_NODES && k < IN_DIM) {
        const float4* p = reinterpret_cast<const float4*>(z + (size_t)m * IN_DIM + k);
        float4 f0 = p[0], f1 = p[1];
        v[0]=f2bf(f0.x); v[1]=f2bf(f0.y); v[2]=f2bf(f0.z); v[3]=f2bf(f0.w);
        v[4]=f2bf(f1.x); v[5]=f2bf(f1.y); v[6]=f2bf(f1.z); v[7]=f2bf(f1.w);
      }
      *reinterpret_cast<short8*>(&As[ar * 40 + ac]) = v;
    }
    // stage B (W tile: all 300 rows, pad to 304)
    #pragma unroll
    for (int p5 = 0; p5 < 5; ++p5) {
      int n = (tid >> 2) + 64 * p5;
      if (n < 304) {
        short8 v = {0,0,0,0,0,0,0,0};
        int k = k0 + ac;
        if (n < OUT_DIM && k < IN_DIM) {
          const float4* p = reinterpret_cast<const float4*>(W + (size_t)n * IN_DIM + k);
          float4 f0 = p[0], f1 = p[1];
          v[0]=f2bf(f0.x); v[1]=f2bf(f0.y); v[2]=f2bf(f0.z); v[3]=f2bf(f0.w);
          v[4]=f2bf(f1.x); v[5]=f2bf(f1.y); v[6]=f2bf(f1.z); v[7]=f2bf(f1.w);
        }
        *reinterpret_cast<short8*>(&Bs[n * 40 + ac]) = v;
      }
    }
    __syncthreads();

    short8 af = *reinterpret_cast<const short8*>(&As[(16 * wid + lr) * 40 + lk]);
    #pragma unroll
    for (int t = 0; t < 19; ++t) {
      short8 bf = *reinterpret_cast<const short8*>(&Bs[(16 * t + lr) * 40 + lk]);
      acc[t] = __builtin_amdgcn_mfma_f32_16x16x32_bf16(af, bf, acc[t], 0, 0, 0);
    }
    __syncthreads();
  }

  // epilogue: D row = 4*(lane>>4)+j, col = lane&15
  const int rbase = m0 + 16 * wid + 4 * (lane >> 4);
  #pragma unroll
  for (int t = 0; t < 19; ++t) {
    int c = 16 * t + lr;
    if (c < OUT_DIM) {
      #pragma unroll
      for (int j = 0; j < 4; ++j) {
        int r = rbase + j;
        if (r < N_NODES) x[(size_t)r * XS + c] = acc[t][j];
      }
    }
  }
}

// ---------------- per-node attention logits a_src/a_dst (one wave per node)
__global__ __launch_bounds__(256) void logits(const float* __restrict__ x,
                                              const float* __restrict__ att_s,
                                              const float* __restrict__ att_d,
                                              float* __restrict__ a_s,
                                              float* __restrict__ a_d) {
  int node = blockIdx.x * 4 + (threadIdx.x >> 6);
  if (node >= N_NODES) return;
  int lane = threadIdx.x & 63;
  float ss = 0.f, sd = 0.f;
  for (int c = lane; c < OUT_DIM; c += 64) {
    float v = x[(size_t)node * XS + c];
    ss += v * att_s[c];
    sd += v * att_d[c];
  }
  ss = wredSumF(ss);
  sd = wredSumF(sd);
  if (lane == 0) { a_s[node] = ss; a_d[node] = sd; }
}

// ---------------- CSR build: histogram, 3-phase scan, scatter-fill
// edge_index arrives as int32 [2, E]: src = ei[e], dst = ei[E + e]
__global__ void hist(const int* __restrict__ ei, int* __restrict__ deg) {
  int e = blockIdx.x * blockDim.x + threadIdx.x;
  if (e < N_EDGES) {
    unsigned dst = (unsigned)ei[N_EDGES + e];
    if (dst < N_NODES) atomicAdd(&deg[dst], 1);   // guard: crash-proof vs dtype surprise
  }
}

#define SCAN_B 1024
#define NBLK   49   // ceil(50000/1024)

__global__ __launch_bounds__(SCAN_B) void scan1(const int* __restrict__ deg,
                                                int* __restrict__ bsum) {
  int i = blockIdx.x * SCAN_B + threadIdx.x;
  int v = (i < N_NODES) ? deg[i] : 0;
  #pragma unroll
  for (int o = 32; o > 0; o >>= 1) v += __shfl_xor(v, o);
  __shared__ int wt[16];
  if ((threadIdx.x & 63) == 0) wt[threadIdx.x >> 6] = v;
  __syncthreads();
  if (threadIdx.x == 0) {
    int t = 0;
    #pragma unroll
    for (int w = 0; w < 16; ++w) t += wt[w];
    bsum[blockIdx.x] = t;
  }
}

__global__ void scan2(const int* __restrict__ bsum, int* __restrict__ bex,
                      int* __restrict__ offs) {
  int l = threadIdx.x;  // 64 threads
  int v = (l < NBLK) ? bsum[l] : 0;
  int incl = v;
  #pragma unroll
  for (int off = 1; off < 64; off <<= 1) {
    int u = __shfl_up(incl, off);
    if (l >= off) incl += u;
  }
  if (l < NBLK) bex[l] = incl - v;
  if (l == NBLK - 1) offs[N_NODES] = incl;   // actual total (== N_EDGES if no drops)
}

__global__ __launch_bounds__(SCAN_B) void scan3(const int* __restrict__ deg,
                                                const int* __restrict__ bex,
                                                int* __restrict__ offs,
                                                int* __restrict__ cursor) {
  int tid = threadIdx.x;
  int i = blockIdx.x * SCAN_B + tid;
  int lane = tid & 63, wid = tid >> 6;
  int v = (i < N_NODES) ? deg[i] : 0;
  int incl = v;
  #pragma unroll
  for (int off = 1; off < 64; off <<= 1) {
    int u = __shfl_up(incl, off);
    if (lane >= off) incl += u;
  }
  __shared__ int wt[16];
  if (lane == 63) wt[wid] = incl;
  __syncthreads();
  if (tid < 16) {
    int t = wt[tid];
    int sc = t;
    #pragma unroll
    for (int off = 1; off < 16; off <<= 1) {
      int u = __shfl_up(sc, off);
      if (tid >= off) sc += u;
    }
    wt[tid] = sc - t;   // exclusive prefix of wave totals
  }
  __syncthreads();
  int excl = incl - v + wt[wid] + bex[blockIdx.x];
  if (i < N_NODES) { offs[i] = excl; cursor[i] = excl; }
}

__global__ void fill(const int* __restrict__ ei, int* __restrict__ cursor,
                     int* __restrict__ srcs) {
  int e = blockIdx.x * blockDim.x + threadIdx.x;
  if (e < N_EDGES) {
    unsigned dst = (unsigned)ei[N_EDGES + e];
    unsigned src = (unsigned)ei[e];
    if (dst < N_NODES && src < N_NODES) {
      int pos = atomicAdd(&cursor[dst], 1);
      srcs[pos] = (int)src;
    }
  }
}

// ---------------- per-node softmax + weighted aggregation (block per node)
#define AGG_T 320
__global__ __launch_bounds__(AGG_T) void aggregate(const float* __restrict__ x,
                                                   const float* __restrict__ a_s,
                                                   const float* __restrict__ a_d,
                                                   const int* __restrict__ offs,
                                                   const int* __restrict__ srcs,
                                                   const float* __restrict__ bias,
                                                   float* __restrict__ out) {
  const int i   = blockIdx.x;
  const int tid = threadIdx.x;
  const int lane = tid & 63, wid = tid >> 6;

  __shared__ float red[8];
  __shared__ float wbuf[AGG_T];
  __shared__ int   sbuf[AGG_T];

  const int beg = offs[i], end = offs[i + 1];
  const int deg = end - beg;
  const float adi = a_d[i];
  const float es  = lrelu(a_s[i] + adi);   // self-loop logit

  // phase A: max logit
  float m = es;
  for (int k = tid; k < deg; k += AGG_T)
    m = fmaxf(m, lrelu(a_s[srcs[beg + k]] + adi));
  m = wredMaxF(m);
  if (lane == 0) red[wid] = m;
  __syncthreads();
  m = fmaxf(fmaxf(fmaxf(red[0], red[1]), fmaxf(red[2], red[3])), red[4]);
  __syncthreads();

  // phase B: sum of exp
  float s = 0.f;
  for (int k = tid; k < deg; k += AGG_T)
    s += expf(lrelu(a_s[srcs[beg + k]] + adi) - m);
  s = wredSumF(s);
  if (lane == 0) red[wid] = s;
  __syncthreads();
  s = red[0] + red[1] + red[2] + red[3] + red[4] + expf(es - m);
  const float inv = 1.0f / s;

  // phase C: weighted gather-accumulate, one column per thread
  const int d = tid;
  float acc = 0.f;
  if (d < OUT_DIM) acc = expf(es - m) * inv * x[(size_t)i * XS + d];

  for (int c0 = 0; c0 < deg; c0 += AGG_T) {
    int cnt = min(AGG_T, deg - c0);
    __syncthreads();
    if (tid < cnt) {
      int sj = srcs[beg + c0 + tid];
      sbuf[tid] = sj;
      wbuf[tid] = expf(lrelu(a_s[sj] + adi) - m) * inv;
    }
    __syncthreads();
    if (d < OUT_DIM) {
      for (int k2 = 0; k2 < cnt; ++k2)
        acc += wbuf[k2] * x[(size_t)sbuf[k2] * XS + d];
    }
  }
  if (d < OUT_DIM) out[(size_t)i * OUT_DIM + d] = acc + bias[d];
}

extern "C" void kernel_launch(void* const* d_in, const int* in_sizes, int n_in,
                              void* d_out, int out_size, void* d_ws, size_t ws_size,
                              hipStream_t stream) {
  const float* z     = (const float*)d_in[0];
  const int*   ei    = (const int*)d_in[1];     // int64 in ref -> int32 on the wire
  const float* W     = (const float*)d_in[2];
  const float* att_s = (const float*)d_in[3];
  const float* att_d = (const float*)d_in[4];
  const float* bias  = (const float*)d_in[5];
  float* out = (float*)d_out;

  char* ws = (char*)d_ws;
  size_t off = 0;
  float* x    = (float*)(ws + off); off += (size_t)N_NODES * XS * 4;   // 60.0 MB
  float* a_s  = (float*)(ws + off); off += 50048 * 4;
  float* a_d  = (float*)(ws + off); off += 50048 * 4;
  int*   deg  = (int*)(ws + off);   off += 50048 * 4;
  int*   offs = (int*)(ws + off);   off += 50056 * 4;                  // N+1
  int*   cur  = (int*)(ws + off);   off += 50048 * 4;
  int*   bsum = (int*)(ws + off);   off += 64 * 4;
  int*   bex  = (int*)(ws + off);   off += 64 * 4;
  int*   srcs = (int*)(ws + off);   off += (size_t)N_EDGES * 4;

  hipMemsetAsync(deg, 0, N_NODES * 4, stream);

  gemm_x<<<(N_NODES + 63) / 64, 256, 0, stream>>>(z, W, x);
  logits<<<N_NODES / 4, 256, 0, stream>>>(x, att_s, att_d, a_s, a_d);
  hist<<<(N_EDGES + 255) / 256, 256, 0, stream>>>(ei, deg);
  scan1<<<NBLK, SCAN_B, 0, stream>>>(deg, bsum);
  scan2<<<1, 64, 0, stream>>>(bsum, bex, offs);
  scan3<<<NBLK, SCAN_B, 0, stream>>>(deg, bex, offs, cur);
  fill<<<(N_EDGES + 255) / 256, 256, 0, stream>>>(ei, cur, srcs);
  aggregate<<<N_NODES, AGG_T, 0, stream>>>(x, a_s, a_d, offs, srcs, bias, out);
}

// Round 3
// 364.261 us; speedup vs baseline: 1.4861x; 1.4861x over previous
//
#include <hip/hip_runtime.h>

#define N_NODES 50000
#define N_EDGES 800000
#define IN_DIM  1200
#define OUT_DIM 300
#define XBS     304                // xb row stride (bf16 elems): 608 B, 16B-aligned
#define NSLOTS  (N_EDGES + N_NODES) // CSR slots incl. one self-loop per node

typedef __attribute__((ext_vector_type(8))) short short8;
typedef __attribute__((ext_vector_type(4))) float f32x4;

__device__ __forceinline__ short f2bf(float f) {
  unsigned u = __builtin_bit_cast(unsigned, f);
  u += 0x7fffu + ((u >> 16) & 1u);            // RNE
  return (short)(u >> 16);
}
__device__ __forceinline__ float bf2f(unsigned short h) {
  return __builtin_bit_cast(float, (unsigned)h << 16);
}
__device__ __forceinline__ float lrelu(float v) { return v > 0.f ? v : 0.2f * v; }

__device__ __forceinline__ float wredMaxF(float v) {
  #pragma unroll
  for (int o = 32; o > 0; o >>= 1) v = fmaxf(v, __shfl_xor(v, o));
  return v;
}
__device__ __forceinline__ float wredSumF(float v) {
  #pragma unroll
  for (int o = 32; o > 0; o >>= 1) v += __shfl_xor(v, o);
  return v;
}

// ---------------- W -> bf16 (padded to 304 rows, zeros beyond 300)
__global__ __launch_bounds__(256) void wconv(const float* __restrict__ W,
                                             unsigned short* __restrict__ Wb) {
  int f = blockIdx.x * 256 + threadIdx.x;          // one short8 per thread
  if (f >= 304 * IN_DIM / 8) return;
  int n = (f * 8) / IN_DIM, c = (f * 8) % IN_DIM;
  short8 v = {0,0,0,0,0,0,0,0};
  if (n < OUT_DIM) {
    const float4* p = reinterpret_cast<const float4*>(W + (size_t)n * IN_DIM + c);
    float4 f0 = p[0], f1 = p[1];
    v[0]=f2bf(f0.x); v[1]=f2bf(f0.y); v[2]=f2bf(f0.z); v[3]=f2bf(f0.w);
    v[4]=f2bf(f1.x); v[5]=f2bf(f1.y); v[6]=f2bf(f1.z); v[7]=f2bf(f1.w);
  }
  *reinterpret_cast<short8*>(&Wb[(size_t)n * IN_DIM + c]) = v;
}

// ---------------- GEMM: xb[50000,300]bf16 = z @ W^T, fused a_s/a_d epilogue
// BM=128, BN=304, BK=32, 256 threads (4 waves, 32 rows each, 2 M-frags x 19 N-frags)
__global__ __launch_bounds__(256, 2) void gemm_x(const float* __restrict__ z,
                                                 const unsigned short* __restrict__ Wb,
                                                 const float* __restrict__ att_s,
                                                 const float* __restrict__ att_d,
                                                 unsigned short* __restrict__ xb,
                                                 float* __restrict__ a_s,
                                                 float* __restrict__ a_d) {
  __shared__ unsigned short As[128 * 40];
  __shared__ unsigned short Bs[304 * 40];

  const int tid  = threadIdx.x;
  const int lane = tid & 63;
  const int wid  = tid >> 6;
  const int m0   = blockIdx.x * 128;
  const int lr   = lane & 15;
  const int lg   = lane >> 4;
  const int lk   = lg * 8;

  f32x4 zero4 = {0.f, 0.f, 0.f, 0.f};
  f32x4 acc[2][19];
  #pragma unroll
  for (int h = 0; h < 2; ++h)
    #pragma unroll
    for (int t = 0; t < 19; ++t) acc[h][t] = zero4;

  const int ar = tid >> 1;            // A stage: row 0..127
  const int ac = (tid & 1) * 16;      // col 0 or 16
  const int bn = tid >> 2;            // B stage: row base
  const int bc = (tid & 3) * 8;       // col 0,8,16,24

  for (int kt = 0; kt < 38; ++kt) {
    const int k0 = kt * 32;
    // stage A: 128x32 f32->bf16, 16 elems/thread
    {
      int m = m0 + ar, k = k0 + ac;
      short8 v0 = {0,0,0,0,0,0,0,0}, v1 = v0;
      if (m < N_NODES && k + 15 < IN_DIM) {
        const float4* p = reinterpret_cast<const float4*>(z + (size_t)m * IN_DIM + k);
        float4 f0 = p[0], f1 = p[1], f2 = p[2], f3 = p[3];
        v0[0]=f2bf(f0.x); v0[1]=f2bf(f0.y); v0[2]=f2bf(f0.z); v0[3]=f2bf(f0.w);
        v0[4]=f2bf(f1.x); v0[5]=f2bf(f1.y); v0[6]=f2bf(f1.z); v0[7]=f2bf(f1.w);
        v1[0]=f2bf(f2.x); v1[1]=f2bf(f2.y); v1[2]=f2bf(f2.z); v1[3]=f2bf(f2.w);
        v1[4]=f2bf(f3.x); v1[5]=f2bf(f3.y); v1[6]=f2bf(f3.z); v1[7]=f2bf(f3.w);
      }
      *reinterpret_cast<short8*>(&As[ar * 40 + ac]) = v0;
      *reinterpret_cast<short8*>(&As[ar * 40 + ac + 8]) = v1;
    }
    // stage B: 304x32 bf16 direct, short8 x5/thread
    #pragma unroll
    for (int p5 = 0; p5 < 5; ++p5) {
      int n = bn + 64 * p5;
      if (n < 304) {
        int k = k0 + bc;
        short8 v = {0,0,0,0,0,0,0,0};
        if (k + 7 < IN_DIM)
          v = *reinterpret_cast<const short8*>(&Wb[(size_t)n * IN_DIM + k]);
        *reinterpret_cast<short8*>(&Bs[n * 40 + bc]) = v;
      }
    }
    __syncthreads();

    short8 af0 = *reinterpret_cast<const short8*>(&As[(32 * wid + lr) * 40 + lk]);
    short8 af1 = *reinterpret_cast<const short8*>(&As[(32 * wid + 16 + lr) * 40 + lk]);
    #pragma unroll
    for (int t = 0; t < 19; ++t) {
      short8 bf = *reinterpret_cast<const short8*>(&Bs[(16 * t + lr) * 40 + lk]);
      acc[0][t] = __builtin_amdgcn_mfma_f32_16x16x32_bf16(af0, bf, acc[0][t], 0, 0, 0);
      acc[1][t] = __builtin_amdgcn_mfma_f32_16x16x32_bf16(af1, bf, acc[1][t], 0, 0, 0);
    }
    __syncthreads();
  }

  // epilogue: store bf16 x, fused logits. D: row=4*lg+j, col=lr within frag.
  #pragma unroll
  for (int h = 0; h < 2; ++h) {
    const int rbase = m0 + 32 * wid + 16 * h + 4 * lg;
    float ps[4] = {0.f,0.f,0.f,0.f}, pd[4] = {0.f,0.f,0.f,0.f};
    #pragma unroll
    for (int t = 0; t < 19; ++t) {
      int c = 16 * t + lr;
      if (c < OUT_DIM) {
        float vs = att_s[c], vd = att_d[c];
        #pragma unroll
        for (int j = 0; j < 4; ++j) {
          float val = acc[h][t][j];
          int r = rbase + j;
          if (r < N_NODES) xb[(size_t)r * XBS + c] = (unsigned short)f2bf(val);
          ps[j] += val * vs;
          pd[j] += val * vd;
        }
      }
    }
    // reduce over lr (16 lanes, same lg-group)
    #pragma unroll
    for (int j = 0; j < 4; ++j) {
      #pragma unroll
      for (int o = 8; o > 0; o >>= 1) {
        ps[j] += __shfl_xor(ps[j], o);
        pd[j] += __shfl_xor(pd[j], o);
      }
    }
    if (lr == 0) {
      #pragma unroll
      for (int j = 0; j < 4; ++j) {
        int r = rbase + j;
        if (r < N_NODES) { a_s[r] = ps[j]; a_d[r] = pd[j]; }
      }
    }
  }
}

// ---------------- CSR build (deg+1 slots per node: +1 self-loop)
__global__ void hist(const int* __restrict__ ei, int* __restrict__ deg) {
  int e = blockIdx.x * blockDim.x + threadIdx.x;
  if (e < N_EDGES) {
    unsigned dst = (unsigned)ei[N_EDGES + e];
    if (dst < N_NODES) atomicAdd(&deg[dst], 1);
  }
}

#define SCAN_B 1024
#define NBLK   49

__global__ __launch_bounds__(SCAN_B) void scan1(const int* __restrict__ deg,
                                                int* __restrict__ bsum) {
  int i = blockIdx.x * SCAN_B + threadIdx.x;
  int v = (i < N_NODES) ? deg[i] + 1 : 0;
  #pragma unroll
  for (int o = 32; o > 0; o >>= 1) v += __shfl_xor(v, o);
  __shared__ int wt[16];
  if ((threadIdx.x & 63) == 0) wt[threadIdx.x >> 6] = v;
  __syncthreads();
  if (threadIdx.x == 0) {
    int t = 0;
    #pragma unroll
    for (int w = 0; w < 16; ++w) t += wt[w];
    bsum[blockIdx.x] = t;
  }
}

__global__ void scan2(const int* __restrict__ bsum, int* __restrict__ bex,
                      int* __restrict__ offs) {
  int l = threadIdx.x;
  int v = (l < NBLK) ? bsum[l] : 0;
  int incl = v;
  #pragma unroll
  for (int off = 1; off < 64; off <<= 1) {
    int u = __shfl_up(incl, off);
    if (l >= off) incl += u;
  }
  if (l < NBLK) bex[l] = incl - v;
  if (l == NBLK - 1) offs[N_NODES] = incl;
}

__global__ __launch_bounds__(SCAN_B) void scan3(const int* __restrict__ deg,
                                                const int* __restrict__ bex,
                                                int* __restrict__ offs,
                                                int* __restrict__ cursor) {
  int tid = threadIdx.x;
  int i = blockIdx.x * SCAN_B + tid;
  int lane = tid & 63, wid = tid >> 6;
  int v = (i < N_NODES) ? deg[i] + 1 : 0;
  int incl = v;
  #pragma unroll
  for (int off = 1; off < 64; off <<= 1) {
    int u = __shfl_up(incl, off);
    if (lane >= off) incl += u;
  }
  __shared__ int wt[16];
  if (lane == 63) wt[wid] = incl;
  __syncthreads();
  if (tid < 16) {
    int t = wt[tid];
    int sc = t;
    #pragma unroll
    for (int off = 1; off < 16; off <<= 1) {
      int u = __shfl_up(sc, off);
      if (tid >= off) sc += u;
    }
    wt[tid] = sc - t;
  }
  __syncthreads();
  int excl = incl - v + wt[wid] + bex[blockIdx.x];
  if (i < N_NODES) { offs[i] = excl; cursor[i] = excl; }
}

__global__ void fill(const int* __restrict__ ei, int* __restrict__ cursor,
                     int* __restrict__ srcs) {
  int e = blockIdx.x * blockDim.x + threadIdx.x;
  if (e < N_EDGES) {
    unsigned dst = (unsigned)ei[N_EDGES + e];
    unsigned src = (unsigned)ei[e];
    if (dst < N_NODES && src < N_NODES) {
      int pos = atomicAdd(&cursor[dst], 1);
      srcs[pos] = (int)src;
    }
  }
}

// ---------------- per-node softmax weights -> packed (src, w), incl self slot
__global__ __launch_bounds__(256) void weights(const float* __restrict__ a_s,
                                               const float* __restrict__ a_d,
                                               const int* __restrict__ offs,
                                               const int* __restrict__ srcs,
                                               int2* __restrict__ packed) {
  int node = blockIdx.x * 4 + (threadIdx.x >> 6);
  if (node >= N_NODES) return;
  int lane = threadIdx.x & 63;
  int beg = offs[node], end = offs[node + 1];
  int ne = end - 1 - beg;                  // true edges (self slot at end-1)
  float adi = a_d[node];
  float eself = lrelu(a_s[node] + adi);

  float m = eself;
  for (int k = lane; k < ne; k += 64)
    m = fmaxf(m, lrelu(a_s[srcs[beg + k]] + adi));
  m = wredMaxF(m);

  float s = 0.f;
  for (int k = lane; k < ne; k += 64)
    s += expf(lrelu(a_s[srcs[beg + k]] + adi) - m);
  s = wredSumF(s) + expf(eself - m);
  float inv = 1.0f / s;

  for (int k = lane; k < ne; k += 64) {
    int sj = srcs[beg + k];
    float w = expf(lrelu(a_s[sj] + adi) - m) * inv;
    packed[beg + k] = make_int2(sj, __float_as_int(w));
  }
  if (lane == 0)
    packed[end - 1] = make_int2(node, __float_as_int(expf(eself - m) * inv));
}

// ---------------- streaming weighted gather: thread = (node, 4-col chunk)
__global__ __launch_bounds__(256) void aggregate(const unsigned short* __restrict__ xb,
                                                 const int2* __restrict__ packed,
                                                 const int* __restrict__ offs,
                                                 const float* __restrict__ bias,
                                                 float* __restrict__ out) {
  unsigned wi = blockIdx.x * 256u + threadIdx.x;
  if (wi >= (unsigned)N_NODES * 75u) return;
  unsigned node = wi / 75u;
  unsigned cc = wi - node * 75u;           // 0..74 -> cols 4cc..4cc+3

  int beg = offs[node], end = offs[node + 1];
  const unsigned short* xcol = xb + 4u * cc;

  float4 acc = {0.f, 0.f, 0.f, 0.f};
  for (int k = beg; k < end; ++k) {
    int2 pw = packed[k];
    float w = __builtin_bit_cast(float, pw.y);
    ushort4 xv = *reinterpret_cast<const ushort4*>(xcol + (size_t)pw.x * XBS);
    acc.x += w * bf2f(xv.x);
    acc.y += w * bf2f(xv.y);
    acc.z += w * bf2f(xv.z);
    acc.w += w * bf2f(xv.w);
  }
  const float4 b = *reinterpret_cast<const float4*>(bias + 4u * cc);
  float4 o = {acc.x + b.x, acc.y + b.y, acc.z + b.z, acc.w + b.w};
  *reinterpret_cast<float4*>(out + (size_t)node * OUT_DIM + 4u * cc) = o;
}

extern "C" void kernel_launch(void* const* d_in, const int* in_sizes, int n_in,
                              void* d_out, int out_size, void* d_ws, size_t ws_size,
                              hipStream_t stream) {
  const float* z     = (const float*)d_in[0];
  const int*   ei    = (const int*)d_in[1];
  const float* W     = (const float*)d_in[2];
  const float* att_s = (const float*)d_in[3];
  const float* att_d = (const float*)d_in[4];
  const float* bias  = (const float*)d_in[5];
  float* out = (float*)d_out;

  char* ws = (char*)d_ws;
  size_t off = 0;
  unsigned short* xb   = (unsigned short*)(ws + off); off += (size_t)N_NODES * XBS * 2;  // 30.4 MB
  unsigned short* Wb   = (unsigned short*)(ws + off); off += (size_t)304 * IN_DIM * 2;   // 0.73 MB
  float* a_s  = (float*)(ws + off); off += 50048 * 4;
  float* a_d  = (float*)(ws + off); off += 50048 * 4;
  int*   deg  = (int*)(ws + off);   off += 50048 * 4;
  int*   offs = (int*)(ws + off);   off += 50056 * 4;
  int*   cur  = (int*)(ws + off);   off += 50048 * 4;
  int*   bsum = (int*)(ws + off);   off += 64 * 4;
  int*   bex  = (int*)(ws + off);   off += 64 * 4;
  int*   srcs = (int*)(ws + off);   off += (size_t)NSLOTS * 4;                           // 3.4 MB
  int2*  pck  = (int2*)(ws + off);  off += (size_t)NSLOTS * 8;                           // 6.8 MB

  hipMemsetAsync(deg, 0, N_NODES * 4, stream);

  wconv<<<(304 * IN_DIM / 8 + 255) / 256, 256, 0, stream>>>(W, Wb);
  gemm_x<<<(N_NODES + 127) / 128, 256, 0, stream>>>(z, Wb, att_s, att_d, xb, a_s, a_d);
  hist<<<(N_EDGES + 255) / 256, 256, 0, stream>>>(ei, deg);
  scan1<<<NBLK, SCAN_B, 0, stream>>>(deg, bsum);
  scan2<<<1, 64, 0, stream>>>(bsum, bex, offs);
  scan3<<<NBLK, SCAN_B, 0, stream>>>(deg, bex, offs, cur);
  fill<<<(N_EDGES + 255) / 256, 256, 0, stream>>>(ei, cur, srcs);
  weights<<<(N_NODES + 3) / 4, 256, 0, stream>>>(a_s, a_d, offs, srcs, pck);
  aggregate<<<((unsigned)N_NODES * 75u + 255) / 256, 256, 0, stream>>>(xb, pck, offs, bias, out);
}

// Round 5
// 363.603 us; speedup vs baseline: 1.4888x; 1.0018x over previous
//
#include <hip/hip_runtime.h>

#define N_NODES 50000
#define N_EDGES 800000
#define IN_DIM  1200
#define KP      1216               // Wb padded K (cols 1200-1215 zero)
#define OUT_DIM 300
#define BNP     320                // Wb padded rows (300-319 zero)
#define XBS     304                // xb row stride (bf16)
#define NSLOTS  (N_EDGES + N_NODES)
#define BM      96
#define GRID_M  ((N_NODES + BM - 1) / BM)   // 521

typedef __attribute__((ext_vector_type(8))) short short8;
typedef __attribute__((ext_vector_type(4))) float f32x4;

__device__ __forceinline__ short f2bf(float f) {
  unsigned u = __builtin_bit_cast(unsigned, f);
  u += 0x7fffu + ((u >> 16) & 1u);            // RNE
  return (short)(u >> 16);
}
__device__ __forceinline__ float bf2f(unsigned short h) {
  return __builtin_bit_cast(float, (unsigned)h << 16);
}
__device__ __forceinline__ float lrelu(float v) { return v > 0.f ? v : 0.2f * v; }

__device__ __forceinline__ float wredMaxF(float v) {
  #pragma unroll
  for (int o = 32; o > 0; o >>= 1) v = fmaxf(v, __shfl_xor(v, o));
  return v;
}
__device__ __forceinline__ float wredSumF(float v) {
  #pragma unroll
  for (int o = 32; o > 0; o >>= 1) v += __shfl_xor(v, o);
  return v;
}

// ---------------- W -> bf16, padded [320][1216]
__global__ __launch_bounds__(256) void wconv(const float* __restrict__ W,
                                             unsigned short* __restrict__ Wb) {
  int f = blockIdx.x * 256 + threadIdx.x;          // one short8 per thread
  if (f >= BNP * KP / 8) return;
  int n = (f * 8) / KP, c = (f * 8) % KP;          // 1200 % 8 == 0: chunks never straddle
  short8 v = {0,0,0,0,0,0,0,0};
  if (n < OUT_DIM && c < IN_DIM) {
    const float4* p = reinterpret_cast<const float4*>(W + (size_t)n * IN_DIM + c);
    float4 f0 = p[0], f1 = p[1];
    v[0]=f2bf(f0.x); v[1]=f2bf(f0.y); v[2]=f2bf(f0.z); v[3]=f2bf(f0.w);
    v[4]=f2bf(f1.x); v[5]=f2bf(f1.y); v[6]=f2bf(f1.z); v[7]=f2bf(f1.w);
  }
  *reinterpret_cast<short8*>(&Wb[(size_t)n * KP + c]) = v;
}

// ---------------- GEMM: xb = z @ W^T (bf16 MFMA), fused a_s/a_d epilogue.
// BM=96, BK=64, 4 waves. N-split: wave w owns N-frags 5w..5w+4 (cols 80w..80w+79),
// all 6 M-frags. A staged in swizzled LDS; B-frags read directly from global (L2-hot).
__global__ __launch_bounds__(256, 2) void gemm_x(const float* __restrict__ z,
                                                 const unsigned short* __restrict__ Wb,
                                                 const float* __restrict__ att_s,
                                                 const float* __restrict__ att_d,
                                                 unsigned short* __restrict__ xb,
                                                 float* __restrict__ a_s,
                                                 float* __restrict__ a_d) {
  __shared__ unsigned short As[BM * 64];    // 12 KB, chunk-XOR swizzled

  const int tid  = threadIdx.x;
  const int lane = tid & 63;
  const int wid  = tid >> 6;
  const int lr   = lane & 15;
  const int lg   = lane >> 4;
  const int m0   = blockIdx.x * BM;

  f32x4 zero4 = {0.f, 0.f, 0.f, 0.f};
  const float4 fz4 = make_float4(0.f, 0.f, 0.f, 0.f);
  f32x4 acc[6][5];
  #pragma unroll
  for (int mf = 0; mf < 6; ++mf)
    #pragma unroll
    for (int nj = 0; nj < 5; ++nj) acc[mf][nj] = zero4;

  // B lane pointer: row = 80*wid + 16*nj + lr, k = kt*64 + ks*32 + lg*8
  const unsigned short* bp = Wb + (size_t)(80 * wid + lr) * KP + lg * 8;

  // A staging: cid = tid + 256*j (j<3); row = cid>>3, ch = cid&7 (8 bf16 per chunk)
  float4 st[3][2];
  const int srow[3] = { (tid + 0)   >> 3, (tid + 256) >> 3, (tid + 512) >> 3 };
  const int sch [3] = { (tid + 0)   & 7,  (tid + 256) & 7,  (tid + 512) & 7  };

  #define LOADST(KT)                                                          \
    _Pragma("unroll")                                                         \
    for (int j = 0; j < 3; ++j) {                                             \
      int m = m0 + srow[j], k = (KT) * 64 + sch[j] * 8;                       \
      if (m < N_NODES && k < IN_DIM) {                                        \
        const float4* p = reinterpret_cast<const float4*>(z + (size_t)m * IN_DIM + k); \
        st[j][0] = p[0]; st[j][1] = p[1];                                     \
      } else { st[j][0] = fz4; st[j][1] = fz4; }                              \
    }

  LOADST(0);

  for (int kt = 0; kt < 19; ++kt) {
    __syncthreads();                       // prev iter's ds_reads done
    #pragma unroll
    for (int j = 0; j < 3; ++j) {
      short8 v;
      v[0]=f2bf(st[j][0].x); v[1]=f2bf(st[j][0].y); v[2]=f2bf(st[j][0].z); v[3]=f2bf(st[j][0].w);
      v[4]=f2bf(st[j][1].x); v[5]=f2bf(st[j][1].y); v[6]=f2bf(st[j][1].z); v[7]=f2bf(st[j][1].w);
      int c2 = sch[j] ^ (srow[j] & 7);     // XOR swizzle
      *reinterpret_cast<short8*>(&As[srow[j] * 64 + c2 * 8]) = v;
    }
    __syncthreads();
    if (kt < 18) { LOADST(kt + 1) }        // issue next tile early (hides HBM latency)

    // preload this wave's 10 B-frags straight from L2
    const unsigned short* bpk = bp + kt * 64;
    short8 bfr[5][2];
    #pragma unroll
    for (int nj = 0; nj < 5; ++nj) {
      bfr[nj][0] = *reinterpret_cast<const short8*>(bpk + (size_t)nj * 16 * KP);
      bfr[nj][1] = *reinterpret_cast<const short8*>(bpk + (size_t)nj * 16 * KP + 32);
    }

    const int sw = lr & 7;
    #pragma unroll
    for (int mf = 0; mf < 6; ++mf) {
      int arow = mf * 16 + lr;
      short8 a0 = *reinterpret_cast<const short8*>(&As[arow * 64 + ((lg    ) ^ sw) * 8]);
      short8 a1 = *reinterpret_cast<const short8*>(&As[arow * 64 + ((4 + lg) ^ sw) * 8]);
      #pragma unroll
      for (int nj = 0; nj < 5; ++nj) {
        acc[mf][nj] = __builtin_amdgcn_mfma_f32_16x16x32_bf16(a0, bfr[nj][0], acc[mf][nj], 0, 0, 0);
        acc[mf][nj] = __builtin_amdgcn_mfma_f32_16x16x32_bf16(a1, bfr[nj][1], acc[mf][nj], 0, 0, 0);
      }
    }
  }
  #undef LOADST

  // ---- epilogue: bf16 x store + fused logits (deterministic cross-wave LDS reduce)
  __syncthreads();                          // done reading As as A-tile
  float* red = reinterpret_cast<float*>(As); // [2][4 waves][96 rows] = 3 KB

  float vs[5], vd[5];
  #pragma unroll
  for (int nj = 0; nj < 5; ++nj) {
    int c = 80 * wid + 16 * nj + lr;
    bool cv = c < OUT_DIM;
    vs[nj] = cv ? att_s[c] : 0.f;
    vd[nj] = cv ? att_d[c] : 0.f;
  }

  #pragma unroll
  for (int mf = 0; mf < 6; ++mf) {
    float ps[4] = {0.f,0.f,0.f,0.f}, pd[4] = {0.f,0.f,0.f,0.f};
    #pragma unroll
    for (int nj = 0; nj < 5; ++nj) {
      int c = 80 * wid + 16 * nj + lr;
      bool cv = c < OUT_DIM;
      #pragma unroll
      for (int jj = 0; jj < 4; ++jj) {
        float val = acc[mf][nj][jj];
        int r = m0 + 16 * mf + 4 * lg + jj;
        if (cv && r < N_NODES) xb[(size_t)r * XBS + c] = (unsigned short)f2bf(val);
        ps[jj] += val * vs[nj];
        pd[jj] += val * vd[nj];
      }
    }
    #pragma unroll
    for (int jj = 0; jj < 4; ++jj) {
      #pragma unroll
      for (int o = 8; o > 0; o >>= 1) {
        ps[jj] += __shfl_xor(ps[jj], o);
        pd[jj] += __shfl_xor(pd[jj], o);
      }
    }
    if (lr == 0) {
      #pragma unroll
      for (int jj = 0; jj < 4; ++jj) {
        int rr = 16 * mf + 4 * lg + jj;
        red[wid * 96 + rr]       = ps[jj];
        red[384 + wid * 96 + rr] = pd[jj];
      }
    }
  }
  __syncthreads();
  if (tid < 96) {
    int r = m0 + tid;
    if (r < N_NODES)
      a_s[r] = red[tid] + red[96 + tid] + red[192 + tid] + red[288 + tid];
  } else if (tid < 192) {
    int t = tid - 96, r = m0 + t;
    if (r < N_NODES)
      a_d[r] = red[384 + t] + red[384 + 96 + t] + red[384 + 192 + t] + red[384 + 288 + t];
  }
}

// ---------------- CSR build (deg+1 slots per node: +1 self-loop)
__global__ void hist(const int* __restrict__ ei, int* __restrict__ deg) {
  int e = blockIdx.x * blockDim.x + threadIdx.x;
  if (e < N_EDGES) {
    unsigned dst = (unsigned)ei[N_EDGES + e];
    if (dst < N_NODES) atomicAdd(&deg[dst], 1);
  }
}

#define SCAN_B 1024
#define NBLK   49

__global__ __launch_bounds__(SCAN_B) void scan1(const int* __restrict__ deg,
                                                int* __restrict__ bsum) {
  int i = blockIdx.x * SCAN_B + threadIdx.x;
  int v = (i < N_NODES) ? deg[i] + 1 : 0;
  #pragma unroll
  for (int o = 32; o > 0; o >>= 1) v += __shfl_xor(v, o);
  __shared__ int wt[16];
  if ((threadIdx.x & 63) == 0) wt[threadIdx.x >> 6] = v;
  __syncthreads();
  if (threadIdx.x == 0) {
    int t = 0;
    #pragma unroll
    for (int w = 0; w < 16; ++w) t += wt[w];
    bsum[blockIdx.x] = t;
  }
}

__global__ void scan2(const int* __restrict__ bsum, int* __restrict__ bex,
                      int* __restrict__ offs) {
  int l = threadIdx.x;
  int v = (l < NBLK) ? bsum[l] : 0;
  int incl = v;
  #pragma unroll
  for (int off = 1; off < 64; off <<= 1) {
    int u = __shfl_up(incl, off);
    if (l >= off) incl += u;
  }
  if (l < NBLK) bex[l] = incl - v;
  if (l == NBLK - 1) offs[N_NODES] = incl;
}

__global__ __launch_bounds__(SCAN_B) void scan3(const int* __restrict__ deg,
                                                const int* __restrict__ bex,
                                                int* __restrict__ offs,
                                                int* __restrict__ cursor) {
  int tid = threadIdx.x;
  int i = blockIdx.x * SCAN_B + tid;
  int lane = tid & 63, wid = tid >> 6;
  int v = (i < N_NODES) ? deg[i] + 1 : 0;
  int incl = v;
  #pragma unroll
  for (int off = 1; off < 64; off <<= 1) {
    int u = __shfl_up(incl, off);
    if (lane >= off) incl += u;
  }
  __shared__ int wt[16];
  if (lane == 63) wt[wid] = incl;
  __syncthreads();
  if (tid < 16) {
    int t = wt[tid];
    int sc = t;
    #pragma unroll
    for (int off = 1; off < 16; off <<= 1) {
      int u = __shfl_up(sc, off);
      if (tid >= off) sc += u;
    }
    wt[tid] = sc - t;
  }
  __syncthreads();
  int excl = incl - v + wt[wid] + bex[blockIdx.x];
  if (i < N_NODES) { offs[i] = excl; cursor[i] = excl; }
}

__global__ void fill(const int* __restrict__ ei, int* __restrict__ cursor,
                     int* __restrict__ srcs) {
  int e = blockIdx.x * blockDim.x + threadIdx.x;
  if (e < N_EDGES) {
    unsigned dst = (unsigned)ei[N_EDGES + e];
    unsigned src = (unsigned)ei[e];
    if (dst < N_NODES && src < N_NODES) {
      int pos = atomicAdd(&cursor[dst], 1);
      srcs[pos] = (int)src;
    }
  }
}

// ---------------- per-node softmax weights -> packed (src, w), incl self slot
__global__ __launch_bounds__(256) void weights(const float* __restrict__ a_s,
                                               const float* __restrict__ a_d,
                                               const int* __restrict__ offs,
                                               const int* __restrict__ srcs,
                                               int2* __restrict__ packed) {
  int node = blockIdx.x * 4 + (threadIdx.x >> 6);
  if (node >= N_NODES) return;
  int lane = threadIdx.x & 63;
  int beg = offs[node], end = offs[node + 1];
  int ne = end - 1 - beg;                  // true edges (self slot at end-1)
  float adi = a_d[node];
  float eself = lrelu(a_s[node] + adi);

  float m = eself;
  for (int k = lane; k < ne; k += 64)
    m = fmaxf(m, lrelu(a_s[srcs[beg + k]] + adi));
  m = wredMaxF(m);

  float s = 0.f;
  for (int k = lane; k < ne; k += 64)
    s += expf(lrelu(a_s[srcs[beg + k]] + adi) - m);
  s = wredSumF(s) + expf(eself - m);
  float inv = 1.0f / s;

  for (int k = lane; k < ne; k += 64) {
    int sj = srcs[beg + k];
    float w = expf(lrelu(a_s[sj] + adi) - m) * inv;
    packed[beg + k] = make_int2(sj, __float_as_int(w));
  }
  if (lane == 0)
    packed[end - 1] = make_int2(node, __float_as_int(expf(eself - m) * inv));
}

// ---------------- streaming weighted gather: thread = (node, 20-col chunk)
#define CCH 15   // chunks per node
__global__ __launch_bounds__(256) void aggregate(const unsigned short* __restrict__ xb,
                                                 const int2* __restrict__ packed,
                                                 const int* __restrict__ offs,
                                                 const float* __restrict__ bias,
                                                 float* __restrict__ out) {
  unsigned wi = blockIdx.x * 256u + threadIdx.x;
  if (wi >= (unsigned)N_NODES * CCH) return;
  unsigned node = wi / CCH;
  unsigned cc = wi - node * CCH;           // 0..14 -> cols 20cc..20cc+19

  int beg = offs[node], end = offs[node + 1];
  const unsigned short* xcol = xb + 20u * cc;

  float acc[20];
  #pragma unroll
  for (int q = 0; q < 20; ++q) acc[q] = 0.f;

  for (int k = beg; k < end; ++k) {
    int2 pw = packed[k];
    float w = __builtin_bit_cast(float, pw.y);
    const unsigned short* xr = xcol + (size_t)pw.x * XBS;
    #pragma unroll
    for (int q = 0; q < 5; ++q) {
      ushort4 xv = *reinterpret_cast<const ushort4*>(xr + 4 * q);
      acc[4*q+0] += w * bf2f(xv.x);
      acc[4*q+1] += w * bf2f(xv.y);
      acc[4*q+2] += w * bf2f(xv.z);
      acc[4*q+3] += w * bf2f(xv.w);
    }
  }
  float* op = out + (size_t)node * OUT_DIM + 20u * cc;
  const float* bp = bias + 20u * cc;
  #pragma unroll
  for (int q = 0; q < 5; ++q) {
    float4 b = *reinterpret_cast<const float4*>(bp + 4 * q);
    float4 o = {acc[4*q] + b.x, acc[4*q+1] + b.y, acc[4*q+2] + b.z, acc[4*q+3] + b.w};
    *reinterpret_cast<float4*>(op + 4 * q) = o;
  }
}

extern "C" void kernel_launch(void* const* d_in, const int* in_sizes, int n_in,
                              void* d_out, int out_size, void* d_ws, size_t ws_size,
                              hipStream_t stream) {
  const float* z     = (const float*)d_in[0];
  const int*   ei    = (const int*)d_in[1];     // int64 in ref -> int32 on the wire
  const float* W     = (const float*)d_in[2];
  const float* att_s = (const float*)d_in[3];
  const float* att_d = (const float*)d_in[4];
  const float* bias  = (const float*)d_in[5];
  float* out = (float*)d_out;

  char* ws = (char*)d_ws;
  size_t off = 0;
  unsigned short* xb = (unsigned short*)(ws + off); off += (size_t)N_NODES * XBS * 2;  // 30.4 MB
  unsigned short* Wb = (unsigned short*)(ws + off); off += (size_t)BNP * KP * 2;       // 0.78 MB
  float* a_s  = (float*)(ws + off); off += 50048 * 4;
  float* a_d  = (float*)(ws + off); off += 50048 * 4;
  int*   deg  = (int*)(ws + off);   off += 50048 * 4;
  int*   offs = (int*)(ws + off);   off += 50056 * 4;
  int*   cur  = (int*)(ws + off);   off += 50048 * 4;
  int*   bsum = (int*)(ws + off);   off += 64 * 4;
  int*   bex  = (int*)(ws + off);   off += 64 * 4;
  int*   srcs = (int*)(ws + off);   off += (size_t)NSLOTS * 4;
  int2*  pck  = (int2*)(ws + off);  off += (size_t)NSLOTS * 8;

  (void)hipMemsetAsync(deg, 0, N_NODES * 4, stream);

  wconv<<<(BNP * KP / 8 + 255) / 256, 256, 0, stream>>>(W, Wb);
  gemm_x<<<GRID_M, 256, 0, stream>>>(z, Wb, att_s, att_d, xb, a_s, a_d);
  hist<<<(N_EDGES + 255) / 256, 256, 0, stream>>>(ei, deg);
  scan1<<<NBLK, SCAN_B, 0, stream>>>(deg, bsum);
  scan2<<<1, 64, 0, stream>>>(bsum, bex, offs);
  scan3<<<NBLK, SCAN_B, 0, stream>>>(deg, bex, offs, cur);
  fill<<<(N_EDGES + 255) / 256, 256, 0, stream>>>(ei, cur, srcs);
  weights<<<(N_NODES + 3) / 4, 256, 0, stream>>>(a_s, a_d, offs, srcs, pck);
  aggregate<<<((unsigned)N_NODES * CCH + 255) / 256, 256, 0, stream>>>(xb, pck, offs, bias, out);
}